// Round 3
// baseline (621.066 us; speedup 1.0000x reference)
//
#include <hip/hip_runtime.h>
#include <hip/hip_bf16.h>

typedef unsigned short u16;
typedef unsigned int u32;
typedef float floatx4 __attribute__((ext_vector_type(4)));
typedef _Float16 f16x8 __attribute__((ext_vector_type(8)));

#define NN 8192
#define DD 512
#define NPARTS 8
#define JCHUNK 1024       // NN / NPARTS
#define RB_PER_PART 171   // 48-row blocks per part: 171*48 >= 8192

__device__ __forceinline__ u16 f2h(float f) {
    _Float16 h = (_Float16)f;                 // RNE
    return __builtin_bit_cast(u16, h);
}
__device__ __forceinline__ float h2f(u16 u) {
    _Float16 h = __builtin_bit_cast(_Float16, u);
    return (float)h;
}

// async 16B-per-lane global->LDS DMA (wave-uniform LDS base + lane*16).
__device__ __forceinline__ void async16(const u16* g, u16* l) {
    __builtin_amdgcn_global_load_lds(
        (const __attribute__((address_space(1))) u32*)g,
        (__attribute__((address_space(3))) u32*)l, 16, 0, 0);
}

// ---------------------------------------------------------------------------
// Projection GEMM, fp16 single-term (fp32 accumulate).  (unchanged)
// z=0: Q = x1@q (row-major fp16), z=1: K = x2@k, z=2: VT = (x1@v)^T
// ---------------------------------------------------------------------------
__global__ __launch_bounds__(256, 2)
void proj_kernel(const float* __restrict__ x1, const float* __restrict__ x2,
                 const float* __restrict__ qw, const float* __restrict__ kw,
                 const float* __restrict__ vw,
                 u16* __restrict__ Qf, u16* __restrict__ Kf, u16* __restrict__ VT)
{
    const int which = blockIdx.z;
    const float* A = (which == 1) ? x2 : x1;
    const float* W = (which == 0) ? qw : (which == 1 ? kw : vw);

    __shared__ u16 Ash[128 * 40];   // [m][k]
    __shared__ u16 Wsh[128 * 40];   // [n][k] (W transposed)

    const int tid  = threadIdx.x;
    const int lane = tid & 63;
    const int wave = tid >> 6;
    const int l15  = lane & 15;
    const int quad = lane >> 4;
    const int wm   = (wave & 1) * 64;
    const int wn   = (wave >> 1) * 64;
    const int m0   = blockIdx.x * 128;
    const int n0   = blockIdx.y * 128;

    floatx4 acc[4][4] = {};

    for (int k0 = 0; k0 < DD; k0 += 32) {
        __syncthreads();
        {   // Stage A tile: 128 x 32 fp32 -> fp16 [m][k]
            const int cg = (tid & 7) * 4;
            for (int i = 0; i < 4; i++) {
                const int row = (tid >> 3) + i * 32;
                float4 f = *(const float4*)&A[(size_t)(m0 + row) * DD + k0 + cg];
                uint2 p;
                p.x = ((unsigned)f2h(f.y) << 16) | f2h(f.x);
                p.y = ((unsigned)f2h(f.w) << 16) | f2h(f.z);
                *(uint2*)&Ash[row * 40 + cg] = p;
            }
        }
        {   // Stage W tile: 32(k) x 128(n) -> fp16 [n][k]
            const int kr = tid & 31;
            const int g  = tid >> 5;
            for (int i = 0; i < 4; i++) {
                const int n = (g + i * 8) * 4;
                float4 f = *(const float4*)&W[(size_t)(k0 + kr) * DD + n0 + n];
                Wsh[(n + 0) * 40 + kr] = f2h(f.x);
                Wsh[(n + 1) * 40 + kr] = f2h(f.y);
                Wsh[(n + 2) * 40 + kr] = f2h(f.z);
                Wsh[(n + 3) * 40 + kr] = f2h(f.w);
            }
        }
        __syncthreads();

        f16x8 af[4], bf[4];
        for (int mi = 0; mi < 4; mi++)
            af[mi] = *(const f16x8*)&Ash[(wm + mi * 16 + l15) * 40 + quad * 8];
        for (int ni = 0; ni < 4; ni++)
            bf[ni] = *(const f16x8*)&Wsh[(wn + ni * 16 + l15) * 40 + quad * 8];
        for (int mi = 0; mi < 4; mi++)
            for (int ni = 0; ni < 4; ni++)
                acc[mi][ni] = __builtin_amdgcn_mfma_f32_16x16x32_f16(
                    af[mi], bf[ni], acc[mi][ni], 0, 0, 0);
    }

    for (int mi = 0; mi < 4; mi++)
        for (int ni = 0; ni < 4; ni++)
            for (int r = 0; r < 4; r++) {
                const int row = m0 + wm + mi * 16 + quad * 4 + r;
                const int col = n0 + wn + ni * 16 + l15;
                const u16 hv = f2h(acc[mi][ni][r]);
                if (which == 0)      Qf[(size_t)row * DD + col] = hv;
                else if (which == 1) Kf[(size_t)row * DD + col] = hv;
                else                 VT[(size_t)col * NN + row] = hv;
            }
}

// ---------------------------------------------------------------------------
// Flash attention partials — producer/consumer waves, MERGED 4-phase schedule.
// R3 delta vs R2: 8 phases/j-iter -> 4 (2 regions staged + 2 quarters
// computed per phase). Barrier-rounds halve (342 -> 171 per CU); each
// release covers 32 ds_read + 32 MFMA (8 independent chains) so ILP covers
// the latency that 2-waves/SIMD TLP cannot. Producer drains vmcnt(0) at
// each barrier (loads age a full phase first); regions staged at p are
// consumed at p+1 — ring conflict-check: pA stage K{2,3} consume K{0,1};
// pB stage V{0,1} consume K{2,3}+softmax; pC stage V{2,3} consume V{0,1};
// pD stage K@jn{0,1} consume V{2,3}.  sched_barrier(0) between quarter
// calls caps the ds_read-hoist register spike (R1 spill lesson: watch
// VGPR_Count==128 and FETCH/WRITE staying at 85/144 MB).
// ---------------------------------------------------------------------------
__global__ __launch_bounds__(256, 2)
void attn_kernel(const u16* __restrict__ Qf, const u16* __restrict__ Kf,
                 const u16* __restrict__ VT,
                 u16* __restrict__ Opart, float* __restrict__ Mp,
                 float* __restrict__ Lp, int* __restrict__ cnt)
{
    const int tid  = threadIdx.x;
    const int lane = tid & 63;
    const int wave = tid >> 6;
    const int l15  = lane & 15;
    const int quad = lane >> 4;

    __shared__ u16 KV[4][8192];         // 4 x 16KB ring
    __shared__ u16 Ps[3][16 * 68];      // per-consumer-wave P transpose
    __shared__ int sPart, sRb;

    // ---- claim work item pinned to this block's physical XCD ----
    if (tid == 0) {
        u32 xcd;
        asm volatile("s_getreg_b32 %0, hwreg(HW_REG_XCC_ID)" : "=s"(xcd));
        xcd &= 7;
        int part = -1, rb = 0;
        for (int t = 0; t < 8; t++) {
            const int p = (xcd + t) & 7;
            const int idx = atomicAdd(&cnt[p], 1);
            if (idx < RB_PER_PART) { part = p; rb = idx; break; }
        }
        sPart = part; sRb = rb;
    }
    __syncthreads();
    const int part = sPart;
    const int rb   = sRb;
    if (part < 0) return;               // unreachable (pigeonhole)

    const bool prod = (wave == 3);

    // consumer Q rows (48 per block; clamp overflow wave of last block —
    // duplicate compute/writes of identical values, benign)
    int q0 = rb * 48 + wave * 16;
    if (q0 > NN - 16) q0 = NN - 16;

    // Q register-resident for consumers (16 A-frags, full D=512)
    f16x8 qf[16];
    if (!prod)
        for (int kk = 0; kk < 16; kk++)
            qf[kk] = *(const f16x8*)&Qf[(size_t)(q0 + l15) * DD + kk * 32 + quad * 8];

    floatx4 o[32] = {};
    float m_run[4], l_run[4];
    for (int r = 0; r < 4; r++) { m_run[r] = -1e30f; l_run[r] = 0.f; }

    const int j_begin = part * JCHUNK;
    const int j_end   = j_begin + JCHUNK;

    // --- producer staging: 16 async16 per region (16KB) ---
    const int krow4  = lane >> 4;        // K: row-sub 0..3
    const int kpos16 = lane & 15;        // K: chunk pos in row
    const int vrs    = lane >> 3;        // V: row-sub 0..7
    const int vch    = (lane & 7) ^ vrs; // V: swizzled source chunk

    auto stageKq = [&](int dq, int j0, int rg) {
        for (int c = 0; c < 16; c++) {
            const int jj  = c * 4;
            const int row = jj + krow4;
            const int sch = kpos16 ^ (row & 7);
            async16(&Kf[(size_t)(j0 + row) * DD + dq * 128 + sch * 8],
                    &KV[rg][jj * 128]);
        }
    };
    auto stageVq = [&](int dq, int j0, int rg) {
        for (int c = 0; c < 16; c++) {
            const int dl = c * 8;
            async16(&VT[(size_t)(dq * 128 + dl + vrs) * NN + j0 + vch * 8],
                    &KV[rg][dl * 64]);
        }
    };

    // --- consumer compute: QK / PV quarters (16 ds_read_b128 + 16 MFMA) ---
    auto qkQ = [&](int rg, int dq, floatx4* s) {
        __builtin_amdgcn_s_setprio(1);
        for (int k8 = 0; k8 < 4; k8++)
            for (int nt = 0; nt < 4; nt++) {
                const int row = nt * 16 + l15;
                const int ch  = (k8 * 4 + quad) ^ (l15 & 7);
                f16x8 b = *(const f16x8*)&KV[rg][row * 128 + ch * 8];
                s[nt] = __builtin_amdgcn_mfma_f32_16x16x32_f16(qf[dq * 4 + k8], b, s[nt], 0, 0, 0);
            }
        __builtin_amdgcn_s_setprio(0);
    };
    auto pvQ = [&](int rg, int dq, f16x8* pf) {
        __builtin_amdgcn_s_setprio(1);
        for (int t = 0; t < 8; t++) {
            const int row = t * 16 + l15;
            const int c0  = quad ^ (l15 & 7);
            const int c1  = (4 + quad) ^ (l15 & 7);
            f16x8 b0 = *(const f16x8*)&KV[rg][row * 64 + c0 * 8];
            f16x8 b1 = *(const f16x8*)&KV[rg][row * 64 + c1 * 8];
            o[dq * 8 + t] = __builtin_amdgcn_mfma_f32_16x16x32_f16(pf[0], b0, o[dq * 8 + t], 0, 0, 0);
            o[dq * 8 + t] = __builtin_amdgcn_mfma_f32_16x16x32_f16(pf[1], b1, o[dq * 8 + t], 0, 0, 0);
        }
        __builtin_amdgcn_s_setprio(0);
    };

    // Merged-phase barrier: producer fully drains its 32-load group (issued
    // a full phase before this wait — not a just-issued drain); consumers
    // do a BARE barrier (no in-loop VMEM).
    auto pbar = [&]() {
        if (prod) asm volatile("s_waitcnt vmcnt(0)" ::: "memory");
        asm volatile("s_barrier" ::: "memory");
    };

    // preamble: producer stages K d0->R0, K d1->R1
    if (prod) { stageKq(0, j_begin, 0); stageKq(1, j_begin, 1); }
    pbar();

    for (int j0 = j_begin; j0 < j_end; j0 += 64) {
        const int jn = (j0 + 64 < j_end) ? j0 + 64 : j_begin;  // wrap: uniform count
        floatx4 s[4] = {};
        f16x8 pf[2];

        // ---- pA: stage K{2,3}; consume QK quarters 0,1 ----
        if (prod) { stageKq(2, j0, 2); stageKq(3, j0, 3); }
        else {
            qkQ(0, 0, s);
            __builtin_amdgcn_sched_barrier(0);
            qkQ(1, 1, s);
        }
        pbar();

        // ---- pB: stage V{0,1}; consume QK quarters 2,3 + softmax + P ----
        if (prod) { stageVq(0, j0, 0); stageVq(1, j0, 1); }
        else {
            qkQ(2, 2, s);
            __builtin_amdgcn_sched_barrier(0);
            qkQ(3, 3, s);

            for (int nt = 0; nt < 4; nt++)
                for (int r = 0; r < 4; r++) {
                    float x = s[nt][r];
                    s[nt][r] = x >= 0.f ? x : 0.01f * x;
                }
            float mt[4];
            for (int r = 0; r < 4; r++)
                mt[r] = fmaxf(fmaxf(s[0][r], s[1][r]), fmaxf(s[2][r], s[3][r]));
            for (int off = 1; off < 16; off <<= 1)
                for (int r = 0; r < 4; r++)
                    mt[r] = fmaxf(mt[r], __shfl_xor(mt[r], off));

            float alpha[4];
            for (int r = 0; r < 4; r++) {
                const float mnew = fmaxf(m_run[r], mt[r]);
                alpha[r] = __expf(m_run[r] - mnew);
                m_run[r] = mnew;
            }
            float ls[4] = {0.f, 0.f, 0.f, 0.f};
            u16 pv[4][4];
            for (int nt = 0; nt < 4; nt++)
                for (int r = 0; r < 4; r++) {
                    const float p = __expf(s[nt][r] - m_run[r]);
                    ls[r] += p;
                    pv[nt][r] = f2h(p);
                }
            for (int off = 1; off < 16; off <<= 1)
                for (int r = 0; r < 4; r++)
                    ls[r] += __shfl_xor(ls[r], off);
            for (int r = 0; r < 4; r++)
                l_run[r] = l_run[r] * alpha[r] + ls[r];
            const bool need = (alpha[0] != 1.f) | (alpha[1] != 1.f) |
                              (alpha[2] != 1.f) | (alpha[3] != 1.f);
            if (__any(need))
                for (int i = 0; i < 32; i++)
                    for (int r = 0; r < 4; r++)
                        o[i][r] *= alpha[r];

            // P: C-layout -> A-layout via per-wave LDS (same-wave, lgkm only)
            for (int nt = 0; nt < 4; nt++)
                for (int r = 0; r < 4; r++)
                    Ps[wave][(quad * 4 + r) * 68 + nt * 16 + l15] = pv[nt][r];
            asm volatile("s_waitcnt lgkmcnt(0)" ::: "memory");
            for (int ks = 0; ks < 2; ks++)
                pf[ks] = *(const f16x8*)&Ps[wave][l15 * 68 + ks * 32 + quad * 8];
        }
        pbar();

        // ---- pC: stage V{2,3}; consume PV quarters 0,1 ----
        if (prod) { stageVq(2, j0, 2); stageVq(3, j0, 3); }
        else {
            pvQ(0, 0, pf);
            __builtin_amdgcn_sched_barrier(0);
            pvQ(1, 1, pf);
        }
        pbar();

        // ---- pD: stage K@jn{0,1}; consume PV quarters 2,3 ----
        if (prod) { stageKq(0, jn, 0); stageKq(1, jn, 1); }
        else {
            pvQ(2, 2, pf);
            __builtin_amdgcn_sched_barrier(0);
            pvQ(3, 3, pf);
        }
        pbar();
    }

    // drain remaining DMA before epilogue / endpgm
    asm volatile("s_waitcnt vmcnt(0)" ::: "memory");

    // ---- consumer epilogue: fp16 un-normalized O + fp32 m,l ----
    if (!prod) {
        for (int i = 0; i < 32; i++)
            for (int r = 0; r < 4; r++) {
                const int row = q0 + quad * 4 + r;
                const int col = i * 16 + l15;
                Opart[((size_t)part * NN + row) * DD + col] = f2h(o[i][r]);
            }
        if (l15 == 0)
            for (int r = 0; r < 4; r++) {
                const int row = q0 + quad * 4 + r;
                Mp[part * NN + row] = m_run[r];
                Lp[part * NN + row] = l_run[r];
            }
    }
}

// ---------------------------------------------------------------------------
// Combine NPARTS j-partials: out = sum_p w_p O_p / sum_p w_p l_p
// R3: vectorized — 64 threads/row, each handling 8 cols via f16x8 loads
// (16B/lane) instead of scalar 2B u16 loads. Grid 2048x256.
// ---------------------------------------------------------------------------
__global__ __launch_bounds__(256)
void combine_kernel(const u16* __restrict__ Opart, const float* __restrict__ Mp,
                    const float* __restrict__ Lp, float* __restrict__ out)
{
    const int t   = blockIdx.x * 256 + threadIdx.x;
    const int row = t >> 6;            // 64 threads per row
    const int c0  = (t & 63) * 8;      // 8 cols per thread

    float m[NPARTS], l[NPARTS];
    float M = -1e30f;
    for (int p = 0; p < NPARTS; p++) {
        m[p] = Mp[p * NN + row];
        l[p] = Lp[p * NN + row];
        M = fmaxf(M, m[p]);
    }
    float w[NPARTS], L = 0.f;
    for (int p = 0; p < NPARTS; p++) { w[p] = __expf(m[p] - M); L += w[p] * l[p]; }
    const float inv = 1.f / L;

    float acc[8] = {};
    for (int p = 0; p < NPARTS; p++) {
        f16x8 v = *(const f16x8*)&Opart[((size_t)p * NN + row) * DD + c0];
        for (int j = 0; j < 8; j++)
            acc[j] += w[p] * (float)v[j];
    }
    float4 o0, o1;
    o0.x = acc[0] * inv; o0.y = acc[1] * inv; o0.z = acc[2] * inv; o0.w = acc[3] * inv;
    o1.x = acc[4] * inv; o1.y = acc[5] * inv; o1.z = acc[6] * inv; o1.w = acc[7] * inv;
    *(float4*)&out[(size_t)row * DD + c0]     = o0;
    *(float4*)&out[(size_t)row * DD + c0 + 4] = o1;
}

// ---------------------------------------------------------------------------
extern "C" void kernel_launch(void* const* d_in, const int* in_sizes, int n_in,
                              void* d_out, int out_size, void* d_ws, size_t ws_size,
                              hipStream_t stream)
{
    const float* x1 = (const float*)d_in[0];
    const float* x2 = (const float*)d_in[1];
    const float* qw = (const float*)d_in[2];
    const float* kw = (const float*)d_in[3];
    const float* vw = (const float*)d_in[4];
    float* out = (float*)d_out;

    // workspace: Qf|Kf|VT (8MB each fp16) | Opart 64MB fp16 | Mp | Lp | cnt[8]
    u16* Qf = (u16*)d_ws;
    u16* Kf = Qf + (size_t)NN * DD;
    u16* VT = Kf + (size_t)NN * DD;
    u16* Opart = VT + (size_t)NN * DD;
    float* Mp = (float*)(Opart + (size_t)NPARTS * NN * DD);
    float* Lp = Mp + NPARTS * NN;
    int* cnt = (int*)(Lp + NPARTS * NN);

    hipMemsetAsync(cnt, 0, NPARTS * sizeof(int), stream);
    proj_kernel<<<dim3(64, 4, 3), 256, 0, stream>>>(x1, x2, qw, kw, vw, Qf, Kf, VT);
    attn_kernel<<<dim3(RB_PER_PART * NPARTS), 256, 0, stream>>>(Qf, Kf, VT, Opart, Mp, Lp, cnt);
    combine_kernel<<<(NN * 64) / 256, 256, 0, stream>>>(Opart, Mp, Lp, out);
}

// Round 4
// 514.296 us; speedup vs baseline: 1.2076x; 1.2076x over previous
//
#include <hip/hip_runtime.h>
#include <hip/hip_bf16.h>

typedef unsigned short u16;
typedef unsigned int u32;
typedef float floatx4 __attribute__((ext_vector_type(4)));
typedef _Float16 f16x8 __attribute__((ext_vector_type(8)));

#define NN 8192
#define DD 512
#define NPARTS 8
#define JCHUNK 1024       // NN / NPARTS
#define RB_PER_PART 128   // 64-row blocks per part: 128*64 == 8192 exactly

__device__ __forceinline__ u16 f2h(float f) {
    _Float16 h = (_Float16)f;                 // RNE
    return __builtin_bit_cast(u16, h);
}
__device__ __forceinline__ float h2f(u16 u) {
    _Float16 h = __builtin_bit_cast(_Float16, u);
    return (float)h;
}

// async 16B-per-lane global->LDS DMA (wave-uniform LDS base + lane*16).
__device__ __forceinline__ void async16(const u16* g, u16* l) {
    __builtin_amdgcn_global_load_lds(
        (const __attribute__((address_space(1))) u32*)g,
        (__attribute__((address_space(3))) u32*)l, 16, 0, 0);
}

// ---------------------------------------------------------------------------
// Projection GEMM, fp16 single-term (fp32 accumulate).  (unchanged)
// z=0: Q = x1@q (row-major fp16), z=1: K = x2@k, z=2: VT = (x1@v)^T
// ---------------------------------------------------------------------------
__global__ __launch_bounds__(256, 2)
void proj_kernel(const float* __restrict__ x1, const float* __restrict__ x2,
                 const float* __restrict__ qw, const float* __restrict__ kw,
                 const float* __restrict__ vw,
                 u16* __restrict__ Qf, u16* __restrict__ Kf, u16* __restrict__ VT)
{
    const int which = blockIdx.z;
    const float* A = (which == 1) ? x2 : x1;
    const float* W = (which == 0) ? qw : (which == 1 ? kw : vw);

    __shared__ u16 Ash[128 * 40];   // [m][k]
    __shared__ u16 Wsh[128 * 40];   // [n][k] (W transposed)

    const int tid  = threadIdx.x;
    const int lane = tid & 63;
    const int wave = tid >> 6;
    const int l15  = lane & 15;
    const int quad = lane >> 4;
    const int wm   = (wave & 1) * 64;
    const int wn   = (wave >> 1) * 64;
    const int m0   = blockIdx.x * 128;
    const int n0   = blockIdx.y * 128;

    floatx4 acc[4][4] = {};

    for (int k0 = 0; k0 < DD; k0 += 32) {
        __syncthreads();
        {   // Stage A tile: 128 x 32 fp32 -> fp16 [m][k]
            const int cg = (tid & 7) * 4;
            for (int i = 0; i < 4; i++) {
                const int row = (tid >> 3) + i * 32;
                float4 f = *(const float4*)&A[(size_t)(m0 + row) * DD + k0 + cg];
                uint2 p;
                p.x = ((unsigned)f2h(f.y) << 16) | f2h(f.x);
                p.y = ((unsigned)f2h(f.w) << 16) | f2h(f.z);
                *(uint2*)&Ash[row * 40 + cg] = p;
            }
        }
        {   // Stage W tile: 32(k) x 128(n) -> fp16 [n][k]
            const int kr = tid & 31;
            const int g  = tid >> 5;
            for (int i = 0; i < 4; i++) {
                const int n = (g + i * 8) * 4;
                float4 f = *(const float4*)&W[(size_t)(k0 + kr) * DD + n0 + n];
                Wsh[(n + 0) * 40 + kr] = f2h(f.x);
                Wsh[(n + 1) * 40 + kr] = f2h(f.y);
                Wsh[(n + 2) * 40 + kr] = f2h(f.z);
                Wsh[(n + 3) * 40 + kr] = f2h(f.w);
            }
        }
        __syncthreads();

        f16x8 af[4], bf[4];
        for (int mi = 0; mi < 4; mi++)
            af[mi] = *(const f16x8*)&Ash[(wm + mi * 16 + l15) * 40 + quad * 8];
        for (int ni = 0; ni < 4; ni++)
            bf[ni] = *(const f16x8*)&Wsh[(wn + ni * 16 + l15) * 40 + quad * 8];
        for (int mi = 0; mi < 4; mi++)
            for (int ni = 0; ni < 4; ni++)
                acc[mi][ni] = __builtin_amdgcn_mfma_f32_16x16x32_f16(
                    af[mi], bf[ni], acc[mi][ni], 0, 0, 0);
    }

    for (int mi = 0; mi < 4; mi++)
        for (int ni = 0; ni < 4; ni++)
            for (int r = 0; r < 4; r++) {
                const int row = m0 + wm + mi * 16 + quad * 4 + r;
                const int col = n0 + wn + ni * 16 + l15;
                const u16 hv = f2h(acc[mi][ni][r]);
                if (which == 0)      Qf[(size_t)row * DD + col] = hv;
                else if (which == 1) Kf[(size_t)row * DD + col] = hv;
                else                 VT[(size_t)col * NN + row] = hv;
            }
}

// ---------------------------------------------------------------------------
// Flash attention partials — ALL-WAVE staging, PROVEN 8-phase depth-2 ring.
// R4: revisit R1's all-wave idea with the spill fixed. R1 spilled because
// staging addresses were recomputed per-load with 64-bit muls inside
// consumer code (~60 extra live regs -> 1.8 GB scratch). Here the per-lane
// staging offsets are PRECOMPUTED into 8 persistent ints (kOff[4]/vOff[4],
// statically indexed) and each phase only forms one wave-uniform base
// pointer (+~10 regs total).  Schedule is byte-identical to R0/R2's proven
// 8-phase: stage region at p, consume at p+2; each wave issues 4 of the 16
// loads per phase, waits vmcnt(4) pre-barrier (newest own group in flight,
// previous group drained -> staged-at-p complete by end of p+1, read at p+2).
// Gains vs R2: 8/8 waves issue MFMA (was 6/8, +33%), blocks 1368 -> 1024 =
// 4.0/CU exactly (tail raggedness gone; barrier-rounds/CU 342 -> 256).
// Tripwire (R1 lesson): FETCH/WRITE must stay ~85/144 MB; if they balloon,
// the spill returned -> producer/consumer split is mandatory.
// ---------------------------------------------------------------------------
__global__ __launch_bounds__(256, 2)
void attn_kernel(const u16* __restrict__ Qf, const u16* __restrict__ Kf,
                 const u16* __restrict__ VT,
                 u16* __restrict__ Opart, float* __restrict__ Mp,
                 float* __restrict__ Lp, int* __restrict__ cnt)
{
    const int tid  = threadIdx.x;
    const int lane = tid & 63;
    const int wave = tid >> 6;
    const int l15  = lane & 15;
    const int quad = lane >> 4;

    __shared__ u16 KV[4][8192];         // 4 x 16KB ring
    __shared__ u16 Ps[4][16 * 68];      // per-wave P transpose
    __shared__ int sPart, sRb;

    // ---- claim work item pinned to this block's physical XCD ----
    if (tid == 0) {
        u32 xcd;
        asm volatile("s_getreg_b32 %0, hwreg(HW_REG_XCC_ID)" : "=s"(xcd));
        xcd &= 7;
        int part = -1, rb = 0;
        for (int t = 0; t < 8; t++) {
            const int p = (xcd + t) & 7;
            const int idx = atomicAdd(&cnt[p], 1);
            if (idx < RB_PER_PART) { part = p; rb = idx; break; }
        }
        sPart = part; sRb = rb;
    }
    __syncthreads();
    const int part = sPart;
    const int rb   = sRb;
    if (part < 0) return;               // unreachable (pigeonhole)

    // 16 Q-rows per wave; 128*64 == 8192 exact, no clamp
    const int q0 = rb * 64 + wave * 16;

    // Q register-resident (16 A-frags, full D=512)
    f16x8 qf[16];
    for (int kk = 0; kk < 16; kk++)
        qf[kk] = *(const f16x8*)&Qf[(size_t)(q0 + l15) * DD + kk * 32 + quad * 8];

    floatx4 o[32] = {};
    float m_run[4], l_run[4];
    for (int r = 0; r < 4; r++) { m_run[r] = -1e30f; l_run[r] = 0.f; }

    const int j_begin = part * JCHUNK;
    const int j_end   = j_begin + JCHUNK;

    // --- staging offsets, precomputed ONCE (8 persistent ints, static idx).
    // This wave covers chunks c = wave*4 + i, i=0..3 of each 16-chunk region.
    const int krow4  = lane >> 4;        // K: row-sub 0..3
    const int kpos16 = lane & 15;        // K: chunk pos in row
    const int vrs    = lane >> 3;        // V: row-sub 0..7
    const int vch    = (lane & 7) ^ vrs; // V: swizzled source chunk

    int kOff[4], vOff[4];
    for (int i = 0; i < 4; i++) {
        const int c    = wave * 4 + i;
        const int krow = c * 4 + krow4;
        kOff[i] = krow * DD + (kpos16 ^ (krow & 7)) * 8;
        vOff[i] = (c * 8 + vrs) * NN + vch * 8;
    }
    // LDS dest for chunk c is KV[rg] + c*512 (u16), identical for K and V.

    auto stageK = [&](int dq, int j0, int rg) {
        const u16* b = Kf + (size_t)j0 * DD + dq * 128;
        u16* d = &KV[rg][wave * 2048];
        async16(b + kOff[0], d);
        async16(b + kOff[1], d + 512);
        async16(b + kOff[2], d + 1024);
        async16(b + kOff[3], d + 1536);
        __builtin_amdgcn_sched_barrier(0);
    };
    auto stageV = [&](int dq, int j0, int rg) {
        const u16* b = VT + (size_t)dq * 128 * NN + j0;
        u16* d = &KV[rg][wave * 2048];
        async16(b + vOff[0], d);
        async16(b + vOff[1], d + 512);
        async16(b + vOff[2], d + 1024);
        async16(b + vOff[3], d + 1536);
        __builtin_amdgcn_sched_barrier(0);
    };

    // --- compute: QK / PV quarters (16 ds_read_b128 + 16 MFMA each) ---
    auto qkQ = [&](int rg, int dq, floatx4* s) {
        __builtin_amdgcn_s_setprio(1);
        for (int k8 = 0; k8 < 4; k8++)
            for (int nt = 0; nt < 4; nt++) {
                const int row = nt * 16 + l15;
                const int ch  = (k8 * 4 + quad) ^ (l15 & 7);
                f16x8 b = *(const f16x8*)&KV[rg][row * 128 + ch * 8];
                s[nt] = __builtin_amdgcn_mfma_f32_16x16x32_f16(qf[dq * 4 + k8], b, s[nt], 0, 0, 0);
            }
        __builtin_amdgcn_s_setprio(0);
    };
    // pf reloaded from Ps inside each PV phase (shortens live range; Ps[wave]
    // is per-wave private and stable until next iter's softmax).
    auto pvQ = [&](int rg, int dq) {
        f16x8 pf0 = *(const f16x8*)&Ps[wave][l15 * 68 + quad * 8];
        f16x8 pf1 = *(const f16x8*)&Ps[wave][l15 * 68 + 32 + quad * 8];
        __builtin_amdgcn_s_setprio(1);
        for (int t = 0; t < 8; t++) {
            const int row = t * 16 + l15;
            const int c0  = quad ^ (l15 & 7);
            const int c1  = (4 + quad) ^ (l15 & 7);
            f16x8 b0 = *(const f16x8*)&KV[rg][row * 64 + c0 * 8];
            f16x8 b1 = *(const f16x8*)&KV[rg][row * 64 + c1 * 8];
            o[dq * 8 + t] = __builtin_amdgcn_mfma_f32_16x16x32_f16(pf0, b0, o[dq * 8 + t], 0, 0, 0);
            o[dq * 8 + t] = __builtin_amdgcn_mfma_f32_16x16x32_f16(pf1, b1, o[dq * 8 + t], 0, 0, 0);
        }
        __builtin_amdgcn_s_setprio(0);
    };

    // Phase barrier: every wave drains all but its newest 4-load group.
    // (Distributed form of R0's producer vmcnt(16) — same depth-2 guarantee:
    // a region staged at p is fully landed by the end of p+1, read at p+2.)
    auto pbar = [&]() {
        asm volatile("s_waitcnt vmcnt(4)" ::: "memory");
        asm volatile("s_barrier" ::: "memory");
    };

    // preamble: stage K d0->R0, K d1->R1
    stageK(0, j_begin, 0);
    stageK(1, j_begin, 1);
    pbar();

    for (int j0 = j_begin; j0 < j_end; j0 += 64) {
        const int jn = (j0 + 64 < j_end) ? j0 + 64 : j_begin;  // wrap: uniform count
        floatx4 s[4] = {};

        stageK(2, j0, 2); qkQ(0, 0, s);  pbar();   // p0
        stageK(3, j0, 3); qkQ(1, 1, s);  pbar();   // p1
        stageV(0, j0, 0); qkQ(2, 2, s);  pbar();   // p2

        // p3: stage V d1; finish QK + softmax + P transpose
        stageV(1, j0, 1);
        qkQ(3, 3, s);

        for (int nt = 0; nt < 4; nt++)
            for (int r = 0; r < 4; r++) {
                float x = s[nt][r];
                s[nt][r] = x >= 0.f ? x : 0.01f * x;
            }
        float mt[4];
        for (int r = 0; r < 4; r++)
            mt[r] = fmaxf(fmaxf(s[0][r], s[1][r]), fmaxf(s[2][r], s[3][r]));
        for (int off = 1; off < 16; off <<= 1)
            for (int r = 0; r < 4; r++)
                mt[r] = fmaxf(mt[r], __shfl_xor(mt[r], off));

        float alpha[4];
        for (int r = 0; r < 4; r++) {
            const float mnew = fmaxf(m_run[r], mt[r]);
            alpha[r] = __expf(m_run[r] - mnew);
            m_run[r] = mnew;
        }
        float ls[4] = {0.f, 0.f, 0.f, 0.f};
        u16 pv[4][4];
        for (int nt = 0; nt < 4; nt++)
            for (int r = 0; r < 4; r++) {
                const float p = __expf(s[nt][r] - m_run[r]);
                ls[r] += p;
                pv[nt][r] = f2h(p);
            }
        for (int off = 1; off < 16; off <<= 1)
            for (int r = 0; r < 4; r++)
                ls[r] += __shfl_xor(ls[r], off);
        for (int r = 0; r < 4; r++)
            l_run[r] = l_run[r] * alpha[r] + ls[r];
        const bool need = (alpha[0] != 1.f) | (alpha[1] != 1.f) |
                          (alpha[2] != 1.f) | (alpha[3] != 1.f);
        if (__any(need))
            for (int i = 0; i < 32; i++)
                for (int r = 0; r < 4; r++)
                    o[i][r] *= alpha[r];

        // P: C-layout -> A-layout via per-wave LDS (same-wave, lgkm only)
        for (int nt = 0; nt < 4; nt++)
            for (int r = 0; r < 4; r++)
                Ps[wave][(quad * 4 + r) * 68 + nt * 16 + l15] = pv[nt][r];
        asm volatile("s_waitcnt lgkmcnt(0)" ::: "memory");

        pbar();                                     // end p3

        stageV(2, j0, 2); pvQ(0, 0);  pbar();   // p4
        stageV(3, j0, 3); pvQ(1, 1);  pbar();   // p5
        stageK(0, jn, 0); pvQ(2, 2);  pbar();   // p6
        stageK(1, jn, 1); pvQ(3, 3);  pbar();   // p7
    }

    // drain remaining DMA before epilogue / endpgm
    asm volatile("s_waitcnt vmcnt(0)" ::: "memory");

    // ---- epilogue: fp16 un-normalized O + fp32 m,l ----
    for (int i = 0; i < 32; i++)
        for (int r = 0; r < 4; r++) {
            const int row = q0 + quad * 4 + r;
            const int col = i * 16 + l15;
            Opart[((size_t)part * NN + row) * DD + col] = f2h(o[i][r]);
        }
    if (l15 == 0)
        for (int r = 0; r < 4; r++) {
            const int row = q0 + quad * 4 + r;
            Mp[part * NN + row] = m_run[r];
            Lp[part * NN + row] = l_run[r];
        }
}

// ---------------------------------------------------------------------------
// Combine NPARTS j-partials: out = sum_p w_p O_p / sum_p w_p l_p
// Vectorized: 64 threads/row, 8 cols/thread via f16x8 (16B/lane).
// ---------------------------------------------------------------------------
__global__ __launch_bounds__(256)
void combine_kernel(const u16* __restrict__ Opart, const float* __restrict__ Mp,
                    const float* __restrict__ Lp, float* __restrict__ out)
{
    const int t   = blockIdx.x * 256 + threadIdx.x;
    const int row = t >> 6;            // 64 threads per row
    const int c0  = (t & 63) * 8;      // 8 cols per thread

    float m[NPARTS], l[NPARTS];
    float M = -1e30f;
    for (int p = 0; p < NPARTS; p++) {
        m[p] = Mp[p * NN + row];
        l[p] = Lp[p * NN + row];
        M = fmaxf(M, m[p]);
    }
    float w[NPARTS], L = 0.f;
    for (int p = 0; p < NPARTS; p++) { w[p] = __expf(m[p] - M); L += w[p] * l[p]; }
    const float inv = 1.f / L;

    float acc[8] = {};
    for (int p = 0; p < NPARTS; p++) {
        f16x8 v = *(const f16x8*)&Opart[((size_t)p * NN + row) * DD + c0];
        for (int j = 0; j < 8; j++)
            acc[j] += w[p] * (float)v[j];
    }
    float4 o0, o1;
    o0.x = acc[0] * inv; o0.y = acc[1] * inv; o0.z = acc[2] * inv; o0.w = acc[3] * inv;
    o1.x = acc[4] * inv; o1.y = acc[5] * inv; o1.z = acc[6] * inv; o1.w = acc[7] * inv;
    *(float4*)&out[(size_t)row * DD + c0]     = o0;
    *(float4*)&out[(size_t)row * DD + c0 + 4] = o1;
}

// ---------------------------------------------------------------------------
extern "C" void kernel_launch(void* const* d_in, const int* in_sizes, int n_in,
                              void* d_out, int out_size, void* d_ws, size_t ws_size,
                              hipStream_t stream)
{
    const float* x1 = (const float*)d_in[0];
    const float* x2 = (const float*)d_in[1];
    const float* qw = (const float*)d_in[2];
    const float* kw = (const float*)d_in[3];
    const float* vw = (const float*)d_in[4];
    float* out = (float*)d_out;

    // workspace: Qf|Kf|VT (8MB each fp16) | Opart 64MB fp16 | Mp | Lp | cnt[8]
    u16* Qf = (u16*)d_ws;
    u16* Kf = Qf + (size_t)NN * DD;
    u16* VT = Kf + (size_t)NN * DD;
    u16* Opart = VT + (size_t)NN * DD;
    float* Mp = (float*)(Opart + (size_t)NPARTS * NN * DD);
    float* Lp = Mp + NPARTS * NN;
    int* cnt = (int*)(Lp + NPARTS * NN);

    hipMemsetAsync(cnt, 0, NPARTS * sizeof(int), stream);
    proj_kernel<<<dim3(64, 4, 3), 256, 0, stream>>>(x1, x2, qw, kw, vw, Qf, Kf, VT);
    attn_kernel<<<dim3(RB_PER_PART * NPARTS), 256, 0, stream>>>(Qf, Kf, VT, Opart, Mp, Lp, cnt);
    combine_kernel<<<(NN * 64) / 256, 256, 0, stream>>>(Opart, Mp, Lp, out);
}

// Round 5
// 495.547 us; speedup vs baseline: 1.2533x; 1.0378x over previous
//
#include <hip/hip_runtime.h>
#include <hip/hip_bf16.h>

typedef unsigned short u16;
typedef unsigned int u32;
typedef float floatx4 __attribute__((ext_vector_type(4)));
typedef _Float16 f16x8 __attribute__((ext_vector_type(8)));

#define NN 8192
#define DD 512
#define NPARTS 4          // R5: 8 -> 4. blocks = 4*128 = 512 = exactly 2/CU,
                          // one uniform generation; Opart/combine traffic halves.
#define JCHUNK 2048       // NN / NPARTS
#define RB_PER_PART 128   // 64-row blocks: 128*64 == 8192 exactly

__device__ __forceinline__ u16 f2h(float f) {
    _Float16 h = (_Float16)f;                 // RNE
    return __builtin_bit_cast(u16, h);
}
__device__ __forceinline__ float h2f(u16 u) {
    _Float16 h = __builtin_bit_cast(_Float16, u);
    return (float)h;
}

// async 16B-per-lane global->LDS DMA (wave-uniform LDS base + lane*16).
__device__ __forceinline__ void async16(const u16* g, u16* l) {
    __builtin_amdgcn_global_load_lds(
        (const __attribute__((address_space(1))) u32*)g,
        (__attribute__((address_space(3))) u32*)l, 16, 0, 0);
}

// ---------------------------------------------------------------------------
// Projection GEMM, fp16 single-term (fp32 accumulate).  (unchanged)
// z=0: Q = x1@q (row-major fp16), z=1: K = x2@k, z=2: VT = (x1@v)^T
// ---------------------------------------------------------------------------
__global__ __launch_bounds__(256, 2)
void proj_kernel(const float* __restrict__ x1, const float* __restrict__ x2,
                 const float* __restrict__ qw, const float* __restrict__ kw,
                 const float* __restrict__ vw,
                 u16* __restrict__ Qf, u16* __restrict__ Kf, u16* __restrict__ VT)
{
    const int which = blockIdx.z;
    const float* A = (which == 1) ? x2 : x1;
    const float* W = (which == 0) ? qw : (which == 1 ? kw : vw);

    __shared__ u16 Ash[128 * 40];   // [m][k]
    __shared__ u16 Wsh[128 * 40];   // [n][k] (W transposed)

    const int tid  = threadIdx.x;
    const int lane = tid & 63;
    const int wave = tid >> 6;
    const int l15  = lane & 15;
    const int quad = lane >> 4;
    const int wm   = (wave & 1) * 64;
    const int wn   = (wave >> 1) * 64;
    const int m0   = blockIdx.x * 128;
    const int n0   = blockIdx.y * 128;

    floatx4 acc[4][4] = {};

    for (int k0 = 0; k0 < DD; k0 += 32) {
        __syncthreads();
        {   // Stage A tile: 128 x 32 fp32 -> fp16 [m][k]
            const int cg = (tid & 7) * 4;
            for (int i = 0; i < 4; i++) {
                const int row = (tid >> 3) + i * 32;
                float4 f = *(const float4*)&A[(size_t)(m0 + row) * DD + k0 + cg];
                uint2 p;
                p.x = ((unsigned)f2h(f.y) << 16) | f2h(f.x);
                p.y = ((unsigned)f2h(f.w) << 16) | f2h(f.z);
                *(uint2*)&Ash[row * 40 + cg] = p;
            }
        }
        {   // Stage W tile: 32(k) x 128(n) -> fp16 [n][k]
            const int kr = tid & 31;
            const int g  = tid >> 5;
            for (int i = 0; i < 4; i++) {
                const int n = (g + i * 8) * 4;
                float4 f = *(const float4*)&W[(size_t)(k0 + kr) * DD + n0 + n];
                Wsh[(n + 0) * 40 + kr] = f2h(f.x);
                Wsh[(n + 1) * 40 + kr] = f2h(f.y);
                Wsh[(n + 2) * 40 + kr] = f2h(f.z);
                Wsh[(n + 3) * 40 + kr] = f2h(f.w);
            }
        }
        __syncthreads();

        f16x8 af[4], bf[4];
        for (int mi = 0; mi < 4; mi++)
            af[mi] = *(const f16x8*)&Ash[(wm + mi * 16 + l15) * 40 + quad * 8];
        for (int ni = 0; ni < 4; ni++)
            bf[ni] = *(const f16x8*)&Wsh[(wn + ni * 16 + l15) * 40 + quad * 8];
        for (int mi = 0; mi < 4; mi++)
            for (int ni = 0; ni < 4; ni++)
                acc[mi][ni] = __builtin_amdgcn_mfma_f32_16x16x32_f16(
                    af[mi], bf[ni], acc[mi][ni], 0, 0, 0);
    }

    for (int mi = 0; mi < 4; mi++)
        for (int ni = 0; ni < 4; ni++)
            for (int r = 0; r < 4; r++) {
                const int row = m0 + wm + mi * 16 + quad * 4 + r;
                const int col = n0 + wn + ni * 16 + l15;
                const u16 hv = f2h(acc[mi][ni][r]);
                if (which == 0)      Qf[(size_t)row * DD + col] = hv;
                else if (which == 1) Kf[(size_t)row * DD + col] = hv;
                else                 VT[(size_t)col * NN + row] = hv;
            }
}

// ---------------------------------------------------------------------------
// Flash attention partials — ALL-WAVE staging, 8-phase depth-2 ring (R4 WIN).
// R5 delta: NPARTS 8 -> 4 only. Inner schedule byte-identical to R4:
// stage region at p (4 async16/wave, precomputed offsets), wait vmcnt(4)
// pre-barrier (newest group in flight, previous drained), consume at p+2.
// NOTE: 8-phase/4x16KB/depth-2 is FORCED by LDS: a merged 4-phase depth-2
// schedule needs 12 live regions x 8KB = 96KB ring > 64KB budget at
// 2 blocks/CU. Registers: o[32]=128 AGPR + 128 VGPR = exactly the 256 cap
// (zero headroom — do not add accumulators).
// Pigeonhole @ NPARTS=4: queue p drained by XCDs p,p+4: 2*32CU*2blk = 128 ✓.
// ---------------------------------------------------------------------------
__global__ __launch_bounds__(256, 2)
void attn_kernel(const u16* __restrict__ Qf, const u16* __restrict__ Kf,
                 const u16* __restrict__ VT,
                 u16* __restrict__ Opart, float* __restrict__ Mp,
                 float* __restrict__ Lp, int* __restrict__ cnt)
{
    const int tid  = threadIdx.x;
    const int lane = tid & 63;
    const int wave = tid >> 6;
    const int l15  = lane & 15;
    const int quad = lane >> 4;

    __shared__ u16 KV[4][8192];         // 4 x 16KB ring
    __shared__ u16 Ps[4][16 * 68];      // per-wave P transpose
    __shared__ int sPart, sRb;

    // ---- claim work item pinned to this block's physical XCD group ----
    if (tid == 0) {
        u32 xcd;
        asm volatile("s_getreg_b32 %0, hwreg(HW_REG_XCC_ID)" : "=s"(xcd));
        xcd &= 3;                       // 4 queues, XCDs p and p+4 share queue p
        int part = -1, rb = 0;
        for (int t = 0; t < 4; t++) {
            const int p = (xcd + t) & 3;
            const int idx = atomicAdd(&cnt[p], 1);
            if (idx < RB_PER_PART) { part = p; rb = idx; break; }
        }
        sPart = part; sRb = rb;
    }
    __syncthreads();
    const int part = sPart;
    const int rb   = sRb;
    if (part < 0) return;               // unreachable (pigeonhole)

    // 16 Q-rows per wave; 128*64 == 8192 exact, no clamp
    const int q0 = rb * 64 + wave * 16;

    // Q register-resident (16 A-frags, full D=512)
    f16x8 qf[16];
    for (int kk = 0; kk < 16; kk++)
        qf[kk] = *(const f16x8*)&Qf[(size_t)(q0 + l15) * DD + kk * 32 + quad * 8];

    floatx4 o[32] = {};
    float m_run[4], l_run[4];
    for (int r = 0; r < 4; r++) { m_run[r] = -1e30f; l_run[r] = 0.f; }

    const int j_begin = part * JCHUNK;
    const int j_end   = j_begin + JCHUNK;

    // --- staging offsets, precomputed ONCE (8 persistent ints, static idx).
    const int krow4  = lane >> 4;        // K: row-sub 0..3
    const int kpos16 = lane & 15;        // K: chunk pos in row
    const int vrs    = lane >> 3;        // V: row-sub 0..7
    const int vch    = (lane & 7) ^ vrs; // V: swizzled source chunk

    int kOff[4], vOff[4];
    for (int i = 0; i < 4; i++) {
        const int c    = wave * 4 + i;
        const int krow = c * 4 + krow4;
        kOff[i] = krow * DD + (kpos16 ^ (krow & 7)) * 8;
        vOff[i] = (c * 8 + vrs) * NN + vch * 8;
    }

    auto stageK = [&](int dq, int j0, int rg) {
        const u16* b = Kf + (size_t)j0 * DD + dq * 128;
        u16* d = &KV[rg][wave * 2048];
        async16(b + kOff[0], d);
        async16(b + kOff[1], d + 512);
        async16(b + kOff[2], d + 1024);
        async16(b + kOff[3], d + 1536);
        __builtin_amdgcn_sched_barrier(0);
    };
    auto stageV = [&](int dq, int j0, int rg) {
        const u16* b = VT + (size_t)dq * 128 * NN + j0;
        u16* d = &KV[rg][wave * 2048];
        async16(b + vOff[0], d);
        async16(b + vOff[1], d + 512);
        async16(b + vOff[2], d + 1024);
        async16(b + vOff[3], d + 1536);
        __builtin_amdgcn_sched_barrier(0);
    };

    // --- compute: QK / PV quarters (16 ds_read_b128 + 16 MFMA each) ---
    auto qkQ = [&](int rg, int dq, floatx4* s) {
        __builtin_amdgcn_s_setprio(1);
        for (int k8 = 0; k8 < 4; k8++)
            for (int nt = 0; nt < 4; nt++) {
                const int row = nt * 16 + l15;
                const int ch  = (k8 * 4 + quad) ^ (l15 & 7);
                f16x8 b = *(const f16x8*)&KV[rg][row * 128 + ch * 8];
                s[nt] = __builtin_amdgcn_mfma_f32_16x16x32_f16(qf[dq * 4 + k8], b, s[nt], 0, 0, 0);
            }
        __builtin_amdgcn_s_setprio(0);
    };
    // pf reloaded from Ps inside each PV phase (shortens live range)
    auto pvQ = [&](int rg, int dq) {
        f16x8 pf0 = *(const f16x8*)&Ps[wave][l15 * 68 + quad * 8];
        f16x8 pf1 = *(const f16x8*)&Ps[wave][l15 * 68 + 32 + quad * 8];
        __builtin_amdgcn_s_setprio(1);
        for (int t = 0; t < 8; t++) {
            const int row = t * 16 + l15;
            const int c0  = quad ^ (l15 & 7);
            const int c1  = (4 + quad) ^ (l15 & 7);
            f16x8 b0 = *(const f16x8*)&KV[rg][row * 64 + c0 * 8];
            f16x8 b1 = *(const f16x8*)&KV[rg][row * 64 + c1 * 8];
            o[dq * 8 + t] = __builtin_amdgcn_mfma_f32_16x16x32_f16(pf0, b0, o[dq * 8 + t], 0, 0, 0);
            o[dq * 8 + t] = __builtin_amdgcn_mfma_f32_16x16x32_f16(pf1, b1, o[dq * 8 + t], 0, 0, 0);
        }
        __builtin_amdgcn_s_setprio(0);
    };

    // Phase barrier: every wave drains all but its newest 4-load group.
    auto pbar = [&]() {
        asm volatile("s_waitcnt vmcnt(4)" ::: "memory");
        asm volatile("s_barrier" ::: "memory");
    };

    // preamble: stage K d0->R0, K d1->R1
    stageK(0, j_begin, 0);
    stageK(1, j_begin, 1);
    pbar();

    for (int j0 = j_begin; j0 < j_end; j0 += 64) {
        const int jn = (j0 + 64 < j_end) ? j0 + 64 : j_begin;  // wrap: uniform count
        floatx4 s[4] = {};

        stageK(2, j0, 2); qkQ(0, 0, s);  pbar();   // p0
        stageK(3, j0, 3); qkQ(1, 1, s);  pbar();   // p1
        stageV(0, j0, 0); qkQ(2, 2, s);  pbar();   // p2

        // p3: stage V d1; finish QK + softmax + P transpose
        stageV(1, j0, 1);
        qkQ(3, 3, s);

        for (int nt = 0; nt < 4; nt++)
            for (int r = 0; r < 4; r++) {
                float x = s[nt][r];
                s[nt][r] = x >= 0.f ? x : 0.01f * x;
            }
        float mt[4];
        for (int r = 0; r < 4; r++)
            mt[r] = fmaxf(fmaxf(s[0][r], s[1][r]), fmaxf(s[2][r], s[3][r]));
        for (int off = 1; off < 16; off <<= 1)
            for (int r = 0; r < 4; r++)
                mt[r] = fmaxf(mt[r], __shfl_xor(mt[r], off));

        float alpha[4];
        for (int r = 0; r < 4; r++) {
            const float mnew = fmaxf(m_run[r], mt[r]);
            alpha[r] = __expf(m_run[r] - mnew);
            m_run[r] = mnew;
        }
        float ls[4] = {0.f, 0.f, 0.f, 0.f};
        u16 pv[4][4];
        for (int nt = 0; nt < 4; nt++)
            for (int r = 0; r < 4; r++) {
                const float p = __expf(s[nt][r] - m_run[r]);
                ls[r] += p;
                pv[nt][r] = f2h(p);
            }
        for (int off = 1; off < 16; off <<= 1)
            for (int r = 0; r < 4; r++)
                ls[r] += __shfl_xor(ls[r], off);
        for (int r = 0; r < 4; r++)
            l_run[r] = l_run[r] * alpha[r] + ls[r];
        const bool need = (alpha[0] != 1.f) | (alpha[1] != 1.f) |
                          (alpha[2] != 1.f) | (alpha[3] != 1.f);
        if (__any(need))
            for (int i = 0; i < 32; i++)
                for (int r = 0; r < 4; r++)
                    o[i][r] *= alpha[r];

        // P: C-layout -> A-layout via per-wave LDS (same-wave, lgkm only)
        for (int nt = 0; nt < 4; nt++)
            for (int r = 0; r < 4; r++)
                Ps[wave][(quad * 4 + r) * 68 + nt * 16 + l15] = pv[nt][r];
        asm volatile("s_waitcnt lgkmcnt(0)" ::: "memory");

        pbar();                                     // end p3

        stageV(2, j0, 2); pvQ(0, 0);  pbar();   // p4
        stageV(3, j0, 3); pvQ(1, 1);  pbar();   // p5
        stageK(0, jn, 0); pvQ(2, 2);  pbar();   // p6
        stageK(1, jn, 1); pvQ(3, 3);  pbar();   // p7
    }

    // drain remaining DMA before epilogue / endpgm
    asm volatile("s_waitcnt vmcnt(0)" ::: "memory");

    // ---- epilogue: fp16 un-normalized O + fp32 m,l ----
    for (int i = 0; i < 32; i++)
        for (int r = 0; r < 4; r++) {
            const int row = q0 + quad * 4 + r;
            const int col = i * 16 + l15;
            Opart[((size_t)part * NN + row) * DD + col] = f2h(o[i][r]);
        }
    if (l15 == 0)
        for (int r = 0; r < 4; r++) {
            const int row = q0 + quad * 4 + r;
            Mp[part * NN + row] = m_run[r];
            Lp[part * NN + row] = l_run[r];
        }
}

// ---------------------------------------------------------------------------
// Combine NPARTS j-partials: out = sum_p w_p O_p / sum_p w_p l_p
// Vectorized: 64 threads/row, 8 cols/thread via f16x8 (16B/lane).
// ---------------------------------------------------------------------------
__global__ __launch_bounds__(256)
void combine_kernel(const u16* __restrict__ Opart, const float* __restrict__ Mp,
                    const float* __restrict__ Lp, float* __restrict__ out)
{
    const int t   = blockIdx.x * 256 + threadIdx.x;
    const int row = t >> 6;            // 64 threads per row
    const int c0  = (t & 63) * 8;      // 8 cols per thread

    float m[NPARTS], l[NPARTS];
    float M = -1e30f;
    for (int p = 0; p < NPARTS; p++) {
        m[p] = Mp[p * NN + row];
        l[p] = Lp[p * NN + row];
        M = fmaxf(M, m[p]);
    }
    float w[NPARTS], L = 0.f;
    for (int p = 0; p < NPARTS; p++) { w[p] = __expf(m[p] - M); L += w[p] * l[p]; }
    const float inv = 1.f / L;

    float acc[8] = {};
    for (int p = 0; p < NPARTS; p++) {
        f16x8 v = *(const f16x8*)&Opart[((size_t)p * NN + row) * DD + c0];
        for (int j = 0; j < 8; j++)
            acc[j] += w[p] * (float)v[j];
    }
    float4 o0, o1;
    o0.x = acc[0] * inv; o0.y = acc[1] * inv; o0.z = acc[2] * inv; o0.w = acc[3] * inv;
    o1.x = acc[4] * inv; o1.y = acc[5] * inv; o1.z = acc[6] * inv; o1.w = acc[7] * inv;
    *(float4*)&out[(size_t)row * DD + c0]     = o0;
    *(float4*)&out[(size_t)row * DD + c0 + 4] = o1;
}

// ---------------------------------------------------------------------------
extern "C" void kernel_launch(void* const* d_in, const int* in_sizes, int n_in,
                              void* d_out, int out_size, void* d_ws, size_t ws_size,
                              hipStream_t stream)
{
    const float* x1 = (const float*)d_in[0];
    const float* x2 = (const float*)d_in[1];
    const float* qw = (const float*)d_in[2];
    const float* kw = (const float*)d_in[3];
    const float* vw = (const float*)d_in[4];
    float* out = (float*)d_out;

    // workspace: Qf|Kf|VT (8MB each fp16) | Opart 32MB fp16 | Mp | Lp | cnt[4]
    u16* Qf = (u16*)d_ws;
    u16* Kf = Qf + (size_t)NN * DD;
    u16* VT = Kf + (size_t)NN * DD;
    u16* Opart = VT + (size_t)NN * DD;
    float* Mp = (float*)(Opart + (size_t)NPARTS * NN * DD);
    float* Lp = Mp + NPARTS * NN;
    int* cnt = (int*)(Lp + NPARTS * NN);

    hipMemsetAsync(cnt, 0, NPARTS * sizeof(int), stream);
    proj_kernel<<<dim3(64, 4, 3), 256, 0, stream>>>(x1, x2, qw, kw, vw, Qf, Kf, VT);
    attn_kernel<<<dim3(RB_PER_PART * NPARTS), 256, 0, stream>>>(Qf, Kf, VT, Opart, Mp, Lp, cnt);
    combine_kernel<<<(NN * 64) / 256, 256, 0, stream>>>(Opart, Mp, Lp, out);
}